// Round 19
// baseline (158.981 us; speedup 1.0000x reference)
//
#include <hip/hip_runtime.h>

// Problem constants
#define L_SEQ 2048
#define DIM   1024
#define NH    16
#define HDIM  64
#define KDIM  1024   // K for both GEMMs

typedef short  short8 __attribute__((ext_vector_type(8)));
typedef __bf16 bf16x8 __attribute__((ext_vector_type(8)));
typedef __bf16 bf16x4 __attribute__((ext_vector_type(4)));
typedef float  f32x4  __attribute__((ext_vector_type(4)));
typedef unsigned u32x4 __attribute__((ext_vector_type(4)));

__device__ __forceinline__ unsigned short f2bf(float f) {
  unsigned u = __builtin_bit_cast(unsigned, f);
  u += 0x7fffu + ((u >> 16) & 1u);   // RNE
  return (unsigned short)(u >> 16);
}

__device__ __forceinline__ void gload16(const void* g, void* l) {
  __builtin_amdgcn_global_load_lds(
      (const __attribute__((address_space(1))) void*)g,
      (__attribute__((address_space(3))) void*)l, 16, 0, 0);
}

__device__ __forceinline__ bf16x8 ldfrag(const unsigned short* p) {
  return __builtin_bit_cast(bf16x8, *(const short8*)p);
}
#define MFMA16(a, b, c) __builtin_amdgcn_mfma_f32_16x16x32_bf16(a, b, c, 0, 0, 0)

// pack two f32 -> one u32 of 2 bf16 (lo = a, hi = b)
__device__ __forceinline__ unsigned cvtpk(float a, float b) {
  unsigned r;
  asm("v_cvt_pk_bf16_f32 %0, %1, %2" : "=v"(r) : "v"(a), "v"(b));
  return r;
}
// safe: operands always hold DIFFERENT values -> no register coalescing hazard
__device__ __forceinline__ void xchg(unsigned &a, unsigned &b) {
  asm("v_permlane32_swap_b32 %0, %1" : "+v"(a), "+v"(b));
  asm("v_permlane16_swap_b32 %0, %1" : "+v"(a), "+v"(b));
}

// 64-lane max across the 4 16-lane groups (== shfl_xor 16 + 32), pure VALU.
__device__ __forceinline__ float foldmax_g(float v) {
  float y;
  asm("v_mov_b32 %0, %1" : "=&v"(y) : "v"(v));
  asm("v_permlane32_swap_b32 %0, %1" : "+v"(v), "+v"(y));
  v = fmaxf(v, y);
  float z;
  asm("v_mov_b32 %0, %1" : "=&v"(z) : "v"(v));
  asm("v_permlane16_swap_b32 %0, %1" : "+v"(v), "+v"(z));
  return fmaxf(v, z);
}

// ---------------- prep: fused fp32->bf16 cvt (x, Wqkv, Wproj) + mask scan ---
// blocks [0,4096): x; [4096,5632): Wqkv; [5632,6144): Wproj; [6144,6148): scan
__device__ __forceinline__ void cvt_chunk(const float* __restrict__ src,
                                          unsigned short* __restrict__ dst,
                                          int blk, int t) {
  int i = (blk * 256 + t) * 8;
  f32x4 a = *(const f32x4*)(src + i);
  f32x4 b = *(const f32x4*)(src + i + 4);
  short8 o;
  o[0] = (short)f2bf(a[0]); o[1] = (short)f2bf(a[1]);
  o[2] = (short)f2bf(a[2]); o[3] = (short)f2bf(a[3]);
  o[4] = (short)f2bf(b[0]); o[5] = (short)f2bf(b[1]);
  o[6] = (short)f2bf(b[2]); o[7] = (short)f2bf(b[3]);
  *(short8*)(dst + i) = o;
}

__global__ __launch_bounds__(256) void prep(
    const float* __restrict__ x, const float* __restrict__ wqkv,
    const float* __restrict__ wproj, const int* __restrict__ mask,
    unsigned short* __restrict__ xb, unsigned short* __restrict__ wqkvb,
    unsigned short* __restrict__ wprojb,
    int* __restrict__ rowl, int* __restrict__ lc) {
  const int bid = blockIdx.x, t = threadIdx.x;
  if (bid < 4096)      { cvt_chunk(x,     xb,     bid,        t); return; }
  if (bid < 5632)      { cvt_chunk(wqkv,  wqkvb,  bid - 4096, t); return; }
  if (bid < 6144)      { cvt_chunk(wproj, wprojb, bid - 5632, t); return; }
  // ---- mask prefix-scan, b = bid - 6144 ----
  const int b = bid - 6144;
  __shared__ int wsum[4];
  __shared__ int lcs;
  const int* mrow = mask + b * L_SEQ + t * 8;
  int m[8], c = 0;
#pragma unroll
  for (int i = 0; i < 8; ++i) { m[i] = mrow[i]; c += (m[i] == 0); }
  const int lane = t & 63, w = t >> 6;
  int sc = c;
#pragma unroll
  for (int d = 1; d < 64; d <<= 1) {
    int v = __shfl_up(sc, d);
    if (lane >= d) sc += v;
  }
  if (lane == 63) wsum[w] = sc;
  __syncthreads();
  int pre = sc - c;
  for (int i = 0; i < w; ++i) pre += wsum[i];
  int run = pre;
#pragma unroll
  for (int i = 0; i < 8; ++i) {
    if (m[i] == 0) { rowl[b * L_SEQ + run] = t * 8 + i; ++run; }
  }
  if (t == 255) { lc[b] = run; lcs = run; }
  __syncthreads();
  int total = lcs;
#pragma unroll
  for (int i = 0; i < 8; ++i) {
    int slot = t * 8 + i;
    if (slot >= total) rowl[b * L_SEQ + slot] = 0;   // safe gather source
  }
}

// ---------------- 128x128 NT GEMM, 512 threads = 8 waves (2M x 4N) ----------
__device__ __forceinline__ void gemm512_mainloop(
    const unsigned short* __restrict__ A, const unsigned short* __restrict__ Bt,
    const int (&asrc)[2], int n0,
    unsigned short* As0, unsigned short* As1,
    unsigned short* Bs0, unsigned short* Bs1,
    f32x4 (&acc)[4][2]) {
  const int t = threadIdx.x;           // 512
  const int lane = t & 63, wid = t >> 6;
  const int wm = wid >> 2, wn = wid & 3;
  const int lr = lane & 15, lk = (lane >> 4) * 8;
  const int swr = (lr & 7) << 3;
  constexpr int NT = KDIM / 64;        // 16

  auto stage = [&](unsigned short* Ad, unsigned short* Bd, int kt) {
#pragma unroll
    for (int i = 0; i < 2; ++i) {
      int c = i * 512 + t;             // 0..1023
      int row = c >> 3;
      int cs = ((c & 7) ^ (row & 7)) * 8;
      gload16(A + (size_t)asrc[i] * KDIM + kt * 64 + cs,
              Ad + row * 64 + (c & 7) * 8);
    }
#pragma unroll
    for (int i = 0; i < 2; ++i) {
      int c = i * 512 + t;
      int row = c >> 3;
      int cs = ((c & 7) ^ (row & 7)) * 8;
      gload16(Bt + (size_t)(n0 + row) * KDIM + kt * 64 + cs,
              Bd + row * 64 + (c & 7) * 8);
    }
  };

  auto tile = [&](const unsigned short* Ac, const unsigned short* Bc,
                  unsigned short* An, unsigned short* Bn, int kt) {
    if (kt + 1 < NT) {
      stage(An, Bn, kt + 1);                           // prefetch next tile
      asm volatile("s_waitcnt vmcnt(4)" ::: "memory"); // current tile landed
    } else {
      asm volatile("s_waitcnt vmcnt(0)" ::: "memory");
    }
    __builtin_amdgcn_sched_barrier(0);
    __builtin_amdgcn_s_barrier();
    __builtin_amdgcn_sched_barrier(0);
    bf16x8 af[4][2], bfv[2][2];
#pragma unroll
    for (int mf = 0; mf < 4; ++mf)
#pragma unroll
      for (int kh = 0; kh < 2; ++kh)
        af[mf][kh] = ldfrag(Ac + (wm * 64 + mf * 16 + lr) * 64 +
                            ((kh * 32 + lk) ^ swr));
#pragma unroll
    for (int nf = 0; nf < 2; ++nf)
#pragma unroll
      for (int kh = 0; kh < 2; ++kh)
        bfv[nf][kh] = ldfrag(Bc + (wn * 32 + nf * 16 + lr) * 64 +
                             ((kh * 32 + lk) ^ swr));
    __builtin_amdgcn_s_setprio(1);
#pragma unroll
    for (int mf = 0; mf < 4; ++mf)
#pragma unroll
      for (int nf = 0; nf < 2; ++nf) {
        acc[mf][nf] = MFMA16(af[mf][0], bfv[nf][0], acc[mf][nf]);
        acc[mf][nf] = MFMA16(af[mf][1], bfv[nf][1], acc[mf][nf]);
      }
    __builtin_amdgcn_s_setprio(0);
    __builtin_amdgcn_sched_barrier(0);
    __builtin_amdgcn_s_barrier();      // reads of current buf retired block-wide
  };

  stage(As0, Bs0, 0);
  for (int kt = 0; kt < NT; kt += 2) {
    tile(As0, Bs0, As1, Bs1, kt);      // read buf0, prefetch into buf1
    tile(As1, Bs1, As0, Bs0, kt + 1);  // read buf1, prefetch into buf0
  }
}

// ---------------- GEMM1: Q (all rows) + K/V (compacted rows) ----------------
__global__ __launch_bounds__(512, 4) void gemm_qkv(
    const unsigned short* __restrict__ xb, const unsigned short* __restrict__ wb,
    const int* __restrict__ rowl, const int* __restrict__ lc,
    unsigned short* __restrict__ qw, unsigned short* __restrict__ kw,
    unsigned short* __restrict__ vtw) {
  __shared__ unsigned short As[2][128 * 64];   // 32 KB
  __shared__ unsigned short Bs[2][128 * 64];   // 32 KB
  const int nx = blockIdx.x;
  const int m0 = blockIdx.y * 128;
  const int sec = nx >> 3;               // 0=Q 1=K 2=V
  const int n0 = nx * 128;
  const int b = m0 >> 11;
  const int lcb = lc[b];
  if (sec > 0 && (m0 & 2047) >= lcb) return;   // fully-dead compacted tile
  const int t = threadIdx.x;
  int asrc[2];
#pragma unroll
  for (int i = 0; i < 2; ++i) {
    int p = m0 + i * 64 + (t >> 3);
    asrc[i] = (sec == 0) ? p : ((p & ~2047) + rowl[p]);
  }
  f32x4 acc[4][2] = {};
  gemm512_mainloop(xb, wb, asrc, n0, As[0], As[1], Bs[0], Bs[1], acc);

  const int lane = t & 63, wid = t >> 6;
  const int wm = wid >> 2, wn = wid & 3;
  const int lr = lane & 15, g4 = (lane >> 4) * 4;
  const int nb = n0 & 1023;
  if (sec == 0) {
#pragma unroll
    for (int mf = 0; mf < 4; ++mf)
#pragma unroll
      for (int nf = 0; nf < 2; ++nf) {
        int e2 = nb + wn * 32 + nf * 16 + lr;
        int h = e2 >> 6, hd = e2 & 63;
#pragma unroll
        for (int r = 0; r < 4; ++r) {
          int m = m0 + wm * 64 + mf * 16 + g4 + r;
          qw[(((size_t)(b * NH + h)) * L_SEQ + (m & 2047)) * HDIM + hd] =
              f2bf(acc[mf][nf][r]);
        }
      }
  } else {
#pragma unroll
    for (int mf = 0; mf < 4; ++mf)
#pragma unroll
      for (int r = 0; r < 4; ++r) {
        int m = m0 + wm * 64 + mf * 16 + g4 + r;
        int tgt = m & 2047;
        size_t bb = (size_t)b * NH;
        if (sec == 1) {
          if (tgt >= lcb) continue;      // K tail: -3e38 overwrite kills it
#pragma unroll
          for (int nf = 0; nf < 2; ++nf) {
            int e2 = nb + wn * 32 + nf * 16 + lr;
            int h = e2 >> 6, hd = e2 & 63;
            kw[((bb + h) * L_SEQ + tgt) * HDIM + hd] = f2bf(acc[mf][nf][r]);
          }
        } else {
          // V: write tail rows as 0 (NaN-safe PV; replaces global zero_buf)
#pragma unroll
          for (int nf = 0; nf < 2; ++nf) {
            int e2 = nb + wn * 32 + nf * 16 + lr;
            int h = e2 >> 6, hd = e2 & 63;
            unsigned short val = (tgt < lcb) ? f2bf(acc[mf][nf][r])
                                             : (unsigned short)0;
            vtw[((bb + h) * HDIM + hd) * L_SEQ + tgt] = val;
          }
        }
      }
  }
}

// ---------------- GEMM2: out = y @ Wproj^T (fp32 out) ----------------
__global__ __launch_bounds__(512, 4) void gemm_proj(
    const unsigned short* __restrict__ yb, const unsigned short* __restrict__ wb,
    float* __restrict__ out) {
  __shared__ unsigned short As[2][128 * 64];
  __shared__ unsigned short Bs[2][128 * 64];
  const int n0 = blockIdx.x * 128, m0 = blockIdx.y * 128;
  const int t = threadIdx.x;
  int asrc[2];
#pragma unroll
  for (int i = 0; i < 2; ++i) asrc[i] = m0 + i * 64 + (t >> 3);
  f32x4 acc[4][2] = {};
  gemm512_mainloop(yb, wb, asrc, n0, As[0], As[1], Bs[0], Bs[1], acc);
  const int lane = t & 63, wid = t >> 6;
  const int wm = wid >> 2, wn = wid & 3;
  const int lr = lane & 15, g4 = (lane >> 4) * 4;
#pragma unroll
  for (int mf = 0; mf < 4; ++mf)
#pragma unroll
    for (int nf = 0; nf < 2; ++nf) {
      int e2 = n0 + wn * 32 + nf * 16 + lr;
#pragma unroll
      for (int r = 0; r < 4; ++r) {
        int m = m0 + wm * 64 + mf * 16 + g4 + r;
        out[(size_t)m * DIM + e2] = acc[mf][nf][r];
      }
    }
}

// ---------------- Flash attention over COMPACTED keys, 8-wave blocks --------
// grid (L/128, B*H) = (16,64) = 1024 blocks x 512 threads; 4 blocks/CU
// (32 KB LDS) x 8 waves = 32 waves/CU (8/SIMD, HW max) -- 2x the r9 wave
// pool. Each wave owns 16 q-rows (qi dim deleted); VGPR must stay <=64.
__global__ __launch_bounds__(512, 8) void attn_kernel(
    const unsigned short* __restrict__ qw, const unsigned short* __restrict__ kw,
    const unsigned short* __restrict__ vtw, const int* __restrict__ lc,
    unsigned short* __restrict__ yb) {
  __shared__ unsigned short Ks[2][64 * 64];    // [buf][kv][hd] swizzled
  __shared__ unsigned short Vts[2][64 * 64];   // [buf][hd][kv] swizzled
  const int bh = blockIdx.y;
  const int q0 = blockIdx.x * 128;
  const int b = bh >> 4, h = bh & 15;
  const int t = threadIdx.x, wid = t >> 6, lane = t & 63;
  const int lr = lane & 15, lk = (lane >> 4) * 8, g4 = (lane >> 4) * 4;
  const int swr = (lr & 7) << 3;
  const float KE = 0.18033688011112042f;    // (1/sqrt(64)) * log2(e)

  const int Lcv = lc[b];
  const int nt = (Lcv + 63) >> 6;           // >=1 (never fully padded)

  // Q fragments: wave owns rows q0 + wid*16 .. +16
  bf16x8 qf[2];
  const size_t qrow = (size_t)bh * L_SEQ + q0 + wid * 16 + lr;
#pragma unroll
  for (int kh = 0; kh < 2; ++kh)
    qf[kh] = __builtin_bit_cast(bf16x8,
        *(const short8*)(qw + qrow * HDIM + kh * 32 + lk));

  f32x4 o[4] = {};
  float mrun = -3.0e38f;
  float lrun = 0.f;                       // lane-partial (folded in epilogue)

  auto stage = [&](int buf, int kt) {
    int row = t >> 3;                     // 0..63
    int cs = ((t & 7) ^ (row & 7)) * 8;
    gload16(kw  + ((size_t)bh * L_SEQ + kt * 64 + row) * HDIM + cs,
            &Ks[buf][t * 8]);
    gload16(vtw + ((size_t)bh * HDIM + row) * L_SEQ + kt * 64 + cs,
            &Vts[buf][t * 8]);
  };

  stage(0, 0);
  int cur = 0;

  for (int kt = 0; kt < nt; ++kt) {
    if (kt + 1 < nt) {
      stage(cur ^ 1, kt + 1);
      asm volatile("s_waitcnt vmcnt(2)" ::: "memory");
    } else {
      asm volatile("s_waitcnt vmcnt(0)" ::: "memory");
    }
    __builtin_amdgcn_s_barrier();
    __builtin_amdgcn_sched_barrier(0);

    const unsigned short* Kc = Ks[cur];
    f32x4 s[4] = {};
    __builtin_amdgcn_s_setprio(1);
#pragma unroll
    for (int nf = 0; nf < 4; ++nf) {
      bf16x8 k0 = __builtin_bit_cast(bf16x8,
          *(const short8*)(Kc + (nf * 16 + lr) * 64 + ((0 + lk) ^ swr)));
      bf16x8 k1 = __builtin_bit_cast(bf16x8,
          *(const short8*)(Kc + (nf * 16 + lr) * 64 + ((32 + lk) ^ swr)));
      s[nf] = MFMA16(k0, qf[0], s[nf]);
      s[nf] = MFMA16(k1, qf[1], s[nf]);
    }
    __builtin_amdgcn_s_setprio(0);

    if (kt == nt - 1) {
      int kbase = kt * 64 + g4;
#pragma unroll
      for (int nf = 0; nf < 4; ++nf)
#pragma unroll
        for (int r = 0; r < 4; ++r)
          if (kbase + nf * 16 + r >= Lcv) s[nf][r] = -3.0e38f;
    }

    float a0 = fmaxf(fmaxf(s[0][0], s[0][1]), fmaxf(s[0][2], s[0][3]));
    float a1 = fmaxf(fmaxf(s[1][0], s[1][1]), fmaxf(s[1][2], s[1][3]));
    float a2 = fmaxf(fmaxf(s[2][0], s[2][1]), fmaxf(s[2][2], s[2][3]));
    float a3 = fmaxf(fmaxf(s[3][0], s[3][1]), fmaxf(s[3][2], s[3][3]));
    float pmax = foldmax_g(fmaxf(fmaxf(a0, a1), fmaxf(a2, a3)));

    if (__any(pmax > mrun + 8.0f)) {
      float mn = fmaxf(mrun, pmax);
      float al = __builtin_amdgcn_exp2f((mrun - mn) * KE);
      mrun = mn;
      lrun *= al;
#pragma unroll
      for (int df = 0; df < 4; ++df) o[df] *= al;
    }

    float mk_ = mrun * KE;
    f32x4 rs4 = {0.f, 0.f, 0.f, 0.f};
#pragma unroll
    for (int nf = 0; nf < 4; ++nf) {
#pragma unroll
      for (int r = 0; r < 4; ++r)
        s[nf][r] = __builtin_amdgcn_exp2f(s[nf][r] * KE - mk_);
      rs4 += s[nf];
    }
    lrun += (rs4[0] + rs4[1]) + (rs4[2] + rs4[3]);   // lane-partial
    unsigned w00 = cvtpk(s[0][0], s[0][1]);
    unsigned w01 = cvtpk(s[0][2], s[0][3]);
    unsigned w10 = cvtpk(s[1][0], s[1][1]);
    unsigned w11 = cvtpk(s[1][2], s[1][3]);
    unsigned w20 = cvtpk(s[2][0], s[2][1]);
    unsigned w21 = cvtpk(s[2][2], s[2][3]);
    unsigned w30 = cvtpk(s[3][0], s[3][1]);
    unsigned w31 = cvtpk(s[3][2], s[3][3]);
    xchg(w00, w10);
    xchg(w01, w11);
    xchg(w20, w30);
    xchg(w21, w31);
    u32x4 f0 = {w00, w01, w10, w11};
    u32x4 f1 = {w20, w21, w30, w31};
    bf16x8 pb0 = __builtin_bit_cast(bf16x8, f0);
    bf16x8 pb1 = __builtin_bit_cast(bf16x8, f1);

    const unsigned short* Vc = Vts[cur];
    __builtin_amdgcn_s_setprio(1);
#pragma unroll
    for (int df = 0; df < 4; ++df) {
      bf16x8 v0 = __builtin_bit_cast(bf16x8,
          *(const short8*)(Vc + (df * 16 + lr) * 64 + ((0 + lk) ^ swr)));
      bf16x8 v1 = __builtin_bit_cast(bf16x8,
          *(const short8*)(Vc + (df * 16 + lr) * 64 + ((32 + lk) ^ swr)));
      o[df] = MFMA16(v0, pb0, o[df]);
      o[df] = MFMA16(v1, pb1, o[df]);
    }
    __builtin_amdgcn_s_setprio(0);

    __builtin_amdgcn_sched_barrier(0);
    __builtin_amdgcn_s_barrier();
    cur ^= 1;
  }

  // epilogue: fold lane-partial lrun across groups ONCE, normalize, write y
  float tot = lrun;
  tot += __shfl_xor(tot, 16);
  tot += __shfl_xor(tot, 32);
  float inv = 1.0f / tot;
  int q = q0 + wid * 16 + lr;
#pragma unroll
  for (int df = 0; df < 4; ++df) {
    bf16x4 pk = {(__bf16)(o[df][0] * inv), (__bf16)(o[df][1] * inv),
                 (__bf16)(o[df][2] * inv), (__bf16)(o[df][3] * inv)};
    *(bf16x4*)(yb + ((size_t)b * L_SEQ + q) * DIM + h * 64 + df * 16 + g4) = pk;
  }
}

// ---------------- launch ----------------
extern "C" void kernel_launch(void* const* d_in, const int* in_sizes, int n_in,
                              void* d_out, int out_size, void* d_ws, size_t ws_size,
                              hipStream_t stream) {
  const float* x     = (const float*)d_in[0];
  const int*   mask  = (const int*)d_in[1];
  const float* wqkv  = (const float*)d_in[2];
  const float* wproj = (const float*)d_in[3];
  char* ws = (char*)d_ws;
  unsigned short* xb     = (unsigned short*)(ws + 0);          // 16 MiB
  unsigned short* wqkvb  = (unsigned short*)(ws + 16777216);   // 6 MiB
  unsigned short* wprojb = (unsigned short*)(ws + 23068672);   // 2 MiB
  unsigned short* qw     = (unsigned short*)(ws + 25165824);   // 16 MiB
  unsigned short* kw     = (unsigned short*)(ws + 41943040);   // 16 MiB
  unsigned short* vtw    = (unsigned short*)(ws + 58720256);   // 16 MiB
  unsigned short* yb     = (unsigned short*)(ws + 75497472);   // 16 MiB
  int*            rowl   = (int*)(ws + 92274688);              // 32 KiB
  int*            lcArr  = (int*)(ws + 92307456);              // 16 B

  prep<<<dim3(6148), 256, 0, stream>>>(x, wqkv, wproj, mask,
                                       xb, wqkvb, wprojb, rowl, lcArr);
  gemm_qkv<<<dim3(24, 64), 512, 0, stream>>>(xb, wqkvb, rowl, lcArr, qw, kw, vtw);
  attn_kernel<<<dim3(16, 64), 512, 0, stream>>>(qw, kw, vtw, lcArr, yb);
  gemm_proj<<<dim3(8, 64), 512, 0, stream>>>(yb, wprojb, (float*)d_out);
}

// Round 20
// 155.058 us; speedup vs baseline: 1.0253x; 1.0253x over previous
//
#include <hip/hip_runtime.h>

// Problem constants
#define L_SEQ 2048
#define DIM   1024
#define NH    16
#define HDIM  64
#define KDIM  1024   // K for both GEMMs

typedef short  short8 __attribute__((ext_vector_type(8)));
typedef __bf16 bf16x8 __attribute__((ext_vector_type(8)));
typedef __bf16 bf16x4 __attribute__((ext_vector_type(4)));
typedef float  f32x4  __attribute__((ext_vector_type(4)));
typedef unsigned u32x4 __attribute__((ext_vector_type(4)));

__device__ __forceinline__ unsigned short f2bf(float f) {
  unsigned u = __builtin_bit_cast(unsigned, f);
  u += 0x7fffu + ((u >> 16) & 1u);   // RNE
  return (unsigned short)(u >> 16);
}

__device__ __forceinline__ void gload16(const void* g, void* l) {
  __builtin_amdgcn_global_load_lds(
      (const __attribute__((address_space(1))) void*)g,
      (__attribute__((address_space(3))) void*)l, 16, 0, 0);
}

__device__ __forceinline__ bf16x8 ldfrag(const unsigned short* p) {
  return __builtin_bit_cast(bf16x8, *(const short8*)p);
}
#define MFMA16(a, b, c) __builtin_amdgcn_mfma_f32_16x16x32_bf16(a, b, c, 0, 0, 0)

// pack two f32 -> one u32 of 2 bf16 (lo = a, hi = b)
__device__ __forceinline__ unsigned cvtpk(float a, float b) {
  unsigned r;
  asm("v_cvt_pk_bf16_f32 %0, %1, %2" : "=v"(r) : "v"(a), "v"(b));
  return r;
}
// safe: operands always hold DIFFERENT values -> no register coalescing hazard
__device__ __forceinline__ void xchg(unsigned &a, unsigned &b) {
  asm("v_permlane32_swap_b32 %0, %1" : "+v"(a), "+v"(b));
  asm("v_permlane16_swap_b32 %0, %1" : "+v"(a), "+v"(b));
}

// 64-lane max across the 4 16-lane groups (== shfl_xor 16 + 32), pure VALU.
__device__ __forceinline__ float foldmax_g(float v) {
  float y;
  asm("v_mov_b32 %0, %1" : "=&v"(y) : "v"(v));
  asm("v_permlane32_swap_b32 %0, %1" : "+v"(v), "+v"(y));
  v = fmaxf(v, y);
  float z;
  asm("v_mov_b32 %0, %1" : "=&v"(z) : "v"(v));
  asm("v_permlane16_swap_b32 %0, %1" : "+v"(v), "+v"(z));
  return fmaxf(v, z);
}

// ---------------- prep: fused fp32->bf16 cvt (x, Wqkv, Wproj) + mask scan ---
__device__ __forceinline__ void cvt_chunk(const float* __restrict__ src,
                                          unsigned short* __restrict__ dst,
                                          int blk, int t) {
  int i = (blk * 256 + t) * 8;
  f32x4 a = *(const f32x4*)(src + i);
  f32x4 b = *(const f32x4*)(src + i + 4);
  short8 o;
  o[0] = (short)f2bf(a[0]); o[1] = (short)f2bf(a[1]);
  o[2] = (short)f2bf(a[2]); o[3] = (short)f2bf(a[3]);
  o[4] = (short)f2bf(b[0]); o[5] = (short)f2bf(b[1]);
  o[6] = (short)f2bf(b[2]); o[7] = (short)f2bf(b[3]);
  *(short8*)(dst + i) = o;
}

__global__ __launch_bounds__(256) void prep(
    const float* __restrict__ x, const float* __restrict__ wqkv,
    const float* __restrict__ wproj, const int* __restrict__ mask,
    unsigned short* __restrict__ xb, unsigned short* __restrict__ wqkvb,
    unsigned short* __restrict__ wprojb,
    int* __restrict__ rowl, int* __restrict__ lc) {
  const int bid = blockIdx.x, t = threadIdx.x;
  if (bid < 4096)      { cvt_chunk(x,     xb,     bid,        t); return; }
  if (bid < 5632)      { cvt_chunk(wqkv,  wqkvb,  bid - 4096, t); return; }
  if (bid < 6144)      { cvt_chunk(wproj, wprojb, bid - 5632, t); return; }
  const int b = bid - 6144;
  __shared__ int wsum[4];
  __shared__ int lcs;
  const int* mrow = mask + b * L_SEQ + t * 8;
  int m[8], c = 0;
#pragma unroll
  for (int i = 0; i < 8; ++i) { m[i] = mrow[i]; c += (m[i] == 0); }
  const int lane = t & 63, w = t >> 6;
  int sc = c;
#pragma unroll
  for (int d = 1; d < 64; d <<= 1) {
    int v = __shfl_up(sc, d);
    if (lane >= d) sc += v;
  }
  if (lane == 63) wsum[w] = sc;
  __syncthreads();
  int pre = sc - c;
  for (int i = 0; i < w; ++i) pre += wsum[i];
  int run = pre;
#pragma unroll
  for (int i = 0; i < 8; ++i) {
    if (m[i] == 0) { rowl[b * L_SEQ + run] = t * 8 + i; ++run; }
  }
  if (t == 255) { lc[b] = run; lcs = run; }
  __syncthreads();
  int total = lcs;
#pragma unroll
  for (int i = 0; i < 8; ++i) {
    int slot = t * 8 + i;
    if (slot >= total) rowl[b * L_SEQ + slot] = 0;   // safe gather source
  }
}

// ---------------- 128x128 NT GEMM, 512 threads = 8 waves (2M x 4N) ----------
__device__ __forceinline__ void gemm512_mainloop(
    const unsigned short* __restrict__ A, const unsigned short* __restrict__ Bt,
    const int (&asrc)[2], int n0,
    unsigned short* As0, unsigned short* As1,
    unsigned short* Bs0, unsigned short* Bs1,
    f32x4 (&acc)[4][2]) {
  const int t = threadIdx.x;           // 512
  const int lane = t & 63, wid = t >> 6;
  const int wm = wid >> 2, wn = wid & 3;
  const int lr = lane & 15, lk = (lane >> 4) * 8;
  const int swr = (lr & 7) << 3;
  constexpr int NT = KDIM / 64;        // 16

  auto stage = [&](unsigned short* Ad, unsigned short* Bd, int kt) {
#pragma unroll
    for (int i = 0; i < 2; ++i) {
      int c = i * 512 + t;             // 0..1023
      int row = c >> 3;
      int cs = ((c & 7) ^ (row & 7)) * 8;
      gload16(A + (size_t)asrc[i] * KDIM + kt * 64 + cs,
              Ad + row * 64 + (c & 7) * 8);
    }
#pragma unroll
    for (int i = 0; i < 2; ++i) {
      int c = i * 512 + t;
      int row = c >> 3;
      int cs = ((c & 7) ^ (row & 7)) * 8;
      gload16(Bt + (size_t)(n0 + row) * KDIM + kt * 64 + cs,
              Bd + row * 64 + (c & 7) * 8);
    }
  };

  auto tile = [&](const unsigned short* Ac, const unsigned short* Bc,
                  unsigned short* An, unsigned short* Bn, int kt) {
    if (kt + 1 < NT) {
      stage(An, Bn, kt + 1);                           // prefetch next tile
      asm volatile("s_waitcnt vmcnt(4)" ::: "memory"); // current tile landed
    } else {
      asm volatile("s_waitcnt vmcnt(0)" ::: "memory");
    }
    __builtin_amdgcn_sched_barrier(0);
    __builtin_amdgcn_s_barrier();
    __builtin_amdgcn_sched_barrier(0);
    bf16x8 af[4][2], bfv[2][2];
#pragma unroll
    for (int mf = 0; mf < 4; ++mf)
#pragma unroll
      for (int kh = 0; kh < 2; ++kh)
        af[mf][kh] = ldfrag(Ac + (wm * 64 + mf * 16 + lr) * 64 +
                            ((kh * 32 + lk) ^ swr));
#pragma unroll
    for (int nf = 0; nf < 2; ++nf)
#pragma unroll
      for (int kh = 0; kh < 2; ++kh)
        bfv[nf][kh] = ldfrag(Bc + (wn * 32 + nf * 16 + lr) * 64 +
                             ((kh * 32 + lk) ^ swr));
    __builtin_amdgcn_s_setprio(1);
#pragma unroll
    for (int mf = 0; mf < 4; ++mf)
#pragma unroll
      for (int nf = 0; nf < 2; ++nf) {
        acc[mf][nf] = MFMA16(af[mf][0], bfv[nf][0], acc[mf][nf]);
        acc[mf][nf] = MFMA16(af[mf][1], bfv[nf][1], acc[mf][nf]);
      }
    __builtin_amdgcn_s_setprio(0);
    __builtin_amdgcn_sched_barrier(0);
    __builtin_amdgcn_s_barrier();      // reads of current buf retired block-wide
  };

  stage(As0, Bs0, 0);
  for (int kt = 0; kt < NT; kt += 2) {
    tile(As0, Bs0, As1, Bs1, kt);      // read buf0, prefetch into buf1
    tile(As1, Bs1, As0, Bs0, kt + 1);  // read buf1, prefetch into buf0
  }
}

// ---------------- GEMM1: Q (all rows) + K/V (compacted rows) ----------------
__global__ __launch_bounds__(512, 4) void gemm_qkv(
    const unsigned short* __restrict__ xb, const unsigned short* __restrict__ wb,
    const int* __restrict__ rowl, const int* __restrict__ lc,
    unsigned short* __restrict__ qw, unsigned short* __restrict__ kw,
    unsigned short* __restrict__ vtw) {
  __shared__ unsigned short As[2][128 * 64];   // 32 KB
  __shared__ unsigned short Bs[2][128 * 64];   // 32 KB
  const int nx = blockIdx.x;
  const int m0 = blockIdx.y * 128;
  const int sec = nx >> 3;               // 0=Q 1=K 2=V
  const int n0 = nx * 128;
  const int b = m0 >> 11;
  const int lcb = lc[b];
  if (sec > 0 && (m0 & 2047) >= lcb) return;   // fully-dead compacted tile
  const int t = threadIdx.x;
  int asrc[2];
#pragma unroll
  for (int i = 0; i < 2; ++i) {
    int p = m0 + i * 64 + (t >> 3);
    asrc[i] = (sec == 0) ? p : ((p & ~2047) + rowl[p]);
  }
  f32x4 acc[4][2] = {};
  gemm512_mainloop(xb, wb, asrc, n0, As[0], As[1], Bs[0], Bs[1], acc);

  const int lane = t & 63, wid = t >> 6;
  const int wm = wid >> 2, wn = wid & 3;
  const int lr = lane & 15, g4 = (lane >> 4) * 4;
  const int nb = n0 & 1023;
  if (sec == 0) {
#pragma unroll
    for (int mf = 0; mf < 4; ++mf)
#pragma unroll
      for (int nf = 0; nf < 2; ++nf) {
        int e2 = nb + wn * 32 + nf * 16 + lr;
        int h = e2 >> 6, hd = e2 & 63;
#pragma unroll
        for (int r = 0; r < 4; ++r) {
          int m = m0 + wm * 64 + mf * 16 + g4 + r;
          qw[(((size_t)(b * NH + h)) * L_SEQ + (m & 2047)) * HDIM + hd] =
              f2bf(acc[mf][nf][r]);
        }
      }
  } else {
#pragma unroll
    for (int mf = 0; mf < 4; ++mf)
#pragma unroll
      for (int r = 0; r < 4; ++r) {
        int m = m0 + wm * 64 + mf * 16 + g4 + r;
        int tgt = m & 2047;
        size_t bb = (size_t)b * NH;
        if (sec == 1) {
          if (tgt >= lcb) continue;      // K tail: -3e38 overwrite kills it
#pragma unroll
          for (int nf = 0; nf < 2; ++nf) {
            int e2 = nb + wn * 32 + nf * 16 + lr;
            int h = e2 >> 6, hd = e2 & 63;
            kw[((bb + h) * L_SEQ + tgt) * HDIM + hd] = f2bf(acc[mf][nf][r]);
          }
        } else {
          // V: write tail rows as 0 (NaN-safe PV; replaces global zero_buf)
#pragma unroll
          for (int nf = 0; nf < 2; ++nf) {
            int e2 = nb + wn * 32 + nf * 16 + lr;
            int h = e2 >> 6, hd = e2 & 63;
            unsigned short val = (tgt < lcb) ? f2bf(acc[mf][nf][r])
                                             : (unsigned short)0;
            vtw[((bb + h) * HDIM + hd) * L_SEQ + tgt] = val;
          }
        }
      }
  }
}

// ---------------- GEMM2: out = y @ Wproj^T (fp32 out) ----------------
__global__ __launch_bounds__(512, 4) void gemm_proj(
    const unsigned short* __restrict__ yb, const unsigned short* __restrict__ wb,
    float* __restrict__ out) {
  __shared__ unsigned short As[2][128 * 64];
  __shared__ unsigned short Bs[2][128 * 64];
  const int n0 = blockIdx.x * 128, m0 = blockIdx.y * 128;
  const int t = threadIdx.x;
  int asrc[2];
#pragma unroll
  for (int i = 0; i < 2; ++i) asrc[i] = m0 + i * 64 + (t >> 3);
  f32x4 acc[4][2] = {};
  gemm512_mainloop(yb, wb, asrc, n0, As[0], As[1], Bs[0], Bs[1], acc);
  const int lane = t & 63, wid = t >> 6;
  const int wm = wid >> 2, wn = wid & 3;
  const int lr = lane & 15, g4 = (lane >> 4) * 4;
#pragma unroll
  for (int mf = 0; mf < 4; ++mf)
#pragma unroll
    for (int nf = 0; nf < 2; ++nf) {
      int e2 = n0 + wn * 32 + nf * 16 + lr;
#pragma unroll
      for (int r = 0; r < 4; ++r) {
        int m = m0 + wm * 64 + mf * 16 + g4 + r;
        out[(size_t)m * DIM + e2] = acc[mf][nf][r];
      }
    }
}

// ---------------- Flash attention over COMPACTED keys (r17 structure) -------
// 256 thr = 4 waves x 32 q-rows; grid (16,64) = 1024 blocks, 4 blocks/CU.
// Lazy max-fold: cross-lane fold only when the defer-max rescale triggers
// (the __any on lane-local max is exactly equivalent to testing the fold).
__global__ __launch_bounds__(256, 4) void attn_kernel(
    const unsigned short* __restrict__ qw, const unsigned short* __restrict__ kw,
    const unsigned short* __restrict__ vtw, const int* __restrict__ lc,
    unsigned short* __restrict__ yb) {
  __shared__ unsigned short Ks[2][64 * 64];    // [buf][kv][hd] swizzled
  __shared__ unsigned short Vts[2][64 * 64];   // [buf][hd][kv] swizzled
  const int bh = blockIdx.y;
  const int q0 = blockIdx.x * 128;
  const int b = bh >> 4, h = bh & 15;
  const int t = threadIdx.x, wid = t >> 6, lane = t & 63;
  const int lr = lane & 15, lk = (lane >> 4) * 8, g4 = (lane >> 4) * 4;
  const int swr = (lr & 7) << 3;
  const float KE = 0.18033688011112042f;    // (1/sqrt(64)) * log2(e)

  const int Lcv = lc[b];
  const int nt = (Lcv + 63) >> 6;           // >=1 (never fully padded)

  bf16x8 qf[2][2];
  const size_t qbase = (size_t)bh * L_SEQ + q0 + wid * 32;
#pragma unroll
  for (int qi = 0; qi < 2; ++qi)
#pragma unroll
    for (int kh = 0; kh < 2; ++kh)
      qf[qi][kh] = __builtin_bit_cast(bf16x8,
          *(const short8*)(qw + (qbase + qi * 16 + lr) * HDIM + kh * 32 + lk));

  f32x4 o[2][4] = {};
  float mrun[2] = {-3.0e38f, -3.0e38f};
  float lrun[2] = {0.f, 0.f};            // LANE-PARTIAL (folded in epilogue)

  auto stage = [&](int buf, int kt) {
#pragma unroll
    for (int i = 0; i < 2; ++i) {
      int c = i * 256 + t;
      int row = c >> 3;
      int cs = ((c & 7) ^ (row & 7)) * 8;
      gload16(kw  + ((size_t)bh * L_SEQ + kt * 64 + row) * HDIM + cs, &Ks[buf][c * 8]);
      gload16(vtw + ((size_t)bh * HDIM + row) * L_SEQ + kt * 64 + cs, &Vts[buf][c * 8]);
    }
  };

  stage(0, 0);
  int cur = 0;

  for (int kt = 0; kt < nt; ++kt) {
    if (kt + 1 < nt) {
      stage(cur ^ 1, kt + 1);
      asm volatile("s_waitcnt vmcnt(4)" ::: "memory");
    } else {
      asm volatile("s_waitcnt vmcnt(0)" ::: "memory");
    }
    __builtin_amdgcn_s_barrier();
    __builtin_amdgcn_sched_barrier(0);

    const unsigned short* Kc = Ks[cur];
    f32x4 s[2][4] = {};
    __builtin_amdgcn_s_setprio(1);
#pragma unroll
    for (int nf = 0; nf < 4; ++nf) {
      bf16x8 k0 = __builtin_bit_cast(bf16x8,
          *(const short8*)(Kc + (nf * 16 + lr) * 64 + ((0 + lk) ^ swr)));
      bf16x8 k1 = __builtin_bit_cast(bf16x8,
          *(const short8*)(Kc + (nf * 16 + lr) * 64 + ((32 + lk) ^ swr)));
      s[0][nf] = MFMA16(k0, qf[0][0], s[0][nf]);
      s[0][nf] = MFMA16(k1, qf[0][1], s[0][nf]);
      s[1][nf] = MFMA16(k0, qf[1][0], s[1][nf]);
      s[1][nf] = MFMA16(k1, qf[1][1], s[1][nf]);
    }
    __builtin_amdgcn_s_setprio(0);

    if (kt == nt - 1) {
      int kbase = kt * 64 + g4;
#pragma unroll
      for (int nf = 0; nf < 4; ++nf)
#pragma unroll
        for (int r = 0; r < 4; ++r)
          if (kbase + nf * 16 + r >= Lcv) {
            s[0][nf][r] = -3.0e38f;
            s[1][nf][r] = -3.0e38f;
          }
    }

    // lane-local max per qi (no cross-lane fold on the fast path)
    float lmax[2];
#pragma unroll
    for (int qi = 0; qi < 2; ++qi) {
      float a0 = fmaxf(fmaxf(s[qi][0][0], s[qi][0][1]), fmaxf(s[qi][0][2], s[qi][0][3]));
      float a1 = fmaxf(fmaxf(s[qi][1][0], s[qi][1][1]), fmaxf(s[qi][1][2], s[qi][1][3]));
      float a2 = fmaxf(fmaxf(s[qi][2][0], s[qi][2][1]), fmaxf(s[qi][2][2], s[qi][2][3]));
      float a3 = fmaxf(fmaxf(s[qi][3][0], s[qi][3][1]), fmaxf(s[qi][3][2], s[qi][3][3]));
      lmax[qi] = fmaxf(fmaxf(a0, a1), fmaxf(a2, a3));
    }

    // defer-max: __any over lane-local max == test on folded max
    bool need = (lmax[0] > mrun[0] + 8.0f) || (lmax[1] > mrun[1] + 8.0f);
    if (__any(need)) {
#pragma unroll
      for (int qi = 0; qi < 2; ++qi) {
        float pmax = foldmax_g(lmax[qi]);          // wave-uniform true max
        float mn = fmaxf(mrun[qi], pmax);
        float al = __builtin_amdgcn_exp2f((mrun[qi] - mn) * KE);
        mrun[qi] = mn;
        lrun[qi] *= al;
#pragma unroll
        for (int df = 0; df < 4; ++df) o[qi][df] *= al;
      }
    }

    bf16x8 pb[2][2];
#pragma unroll
    for (int qi = 0; qi < 2; ++qi) {
      float mk_ = mrun[qi] * KE;
      f32x4 rs4 = {0.f, 0.f, 0.f, 0.f};
#pragma unroll
      for (int nf = 0; nf < 4; ++nf) {
#pragma unroll
        for (int r = 0; r < 4; ++r)
          s[qi][nf][r] = __builtin_amdgcn_exp2f(s[qi][nf][r] * KE - mk_);
        rs4 += s[qi][nf];
      }
      lrun[qi] += (rs4[0] + rs4[1]) + (rs4[2] + rs4[3]);  // lane-partial
      unsigned w00 = cvtpk(s[qi][0][0], s[qi][0][1]);
      unsigned w01 = cvtpk(s[qi][0][2], s[qi][0][3]);
      unsigned w10 = cvtpk(s[qi][1][0], s[qi][1][1]);
      unsigned w11 = cvtpk(s[qi][1][2], s[qi][1][3]);
      unsigned w20 = cvtpk(s[qi][2][0], s[qi][2][1]);
      unsigned w21 = cvtpk(s[qi][2][2], s[qi][2][3]);
      unsigned w30 = cvtpk(s[qi][3][0], s[qi][3][1]);
      unsigned w31 = cvtpk(s[qi][3][2], s[qi][3][3]);
      xchg(w00, w10);
      xchg(w01, w11);
      xchg(w20, w30);
      xchg(w21, w31);
      u32x4 f0 = {w00, w01, w10, w11};
      u32x4 f1 = {w20, w21, w30, w31};
      pb[qi][0] = __builtin_bit_cast(bf16x8, f0);
      pb[qi][1] = __builtin_bit_cast(bf16x8, f1);
    }

    const unsigned short* Vc = Vts[cur];
    __builtin_amdgcn_s_setprio(1);
#pragma unroll
    for (int df = 0; df < 4; ++df) {
      bf16x8 v0 = __builtin_bit_cast(bf16x8,
          *(const short8*)(Vc + (df * 16 + lr) * 64 + ((0 + lk) ^ swr)));
      bf16x8 v1 = __builtin_bit_cast(bf16x8,
          *(const short8*)(Vc + (df * 16 + lr) * 64 + ((32 + lk) ^ swr)));
      o[0][df] = MFMA16(v0, pb[0][0], o[0][df]);
      o[0][df] = MFMA16(v1, pb[0][1], o[0][df]);
      o[1][df] = MFMA16(v0, pb[1][0], o[1][df]);
      o[1][df] = MFMA16(v1, pb[1][1], o[1][df]);
    }
    __builtin_amdgcn_s_setprio(0);

    __builtin_amdgcn_sched_barrier(0);
    __builtin_amdgcn_s_barrier();
    cur ^= 1;
  }

  // epilogue: fold lane-partial lrun across groups ONCE, normalize, write y
#pragma unroll
  for (int qi = 0; qi < 2; ++qi) {
    float tot = lrun[qi];
    tot += __shfl_xor(tot, 16);
    tot += __shfl_xor(tot, 32);
    float inv = 1.0f / tot;
    int q = q0 + wid * 32 + qi * 16 + lr;
#pragma unroll
    for (int df = 0; df < 4; ++df) {
      bf16x4 pk = {(__bf16)(o[qi][df][0] * inv), (__bf16)(o[qi][df][1] * inv),
                   (__bf16)(o[qi][df][2] * inv), (__bf16)(o[qi][df][3] * inv)};
      *(bf16x4*)(yb + ((size_t)b * L_SEQ + q) * DIM + h * 64 + df * 16 + g4) = pk;
    }
  }
}

// ---------------- launch ----------------
extern "C" void kernel_launch(void* const* d_in, const int* in_sizes, int n_in,
                              void* d_out, int out_size, void* d_ws, size_t ws_size,
                              hipStream_t stream) {
  const float* x     = (const float*)d_in[0];
  const int*   mask  = (const int*)d_in[1];
  const float* wqkv  = (const float*)d_in[2];
  const float* wproj = (const float*)d_in[3];
  char* ws = (char*)d_ws;
  unsigned short* xb     = (unsigned short*)(ws + 0);          // 16 MiB
  unsigned short* wqkvb  = (unsigned short*)(ws + 16777216);   // 6 MiB
  unsigned short* wprojb = (unsigned short*)(ws + 23068672);   // 2 MiB
  unsigned short* qw     = (unsigned short*)(ws + 25165824);   // 16 MiB
  unsigned short* kw     = (unsigned short*)(ws + 41943040);   // 16 MiB
  unsigned short* vtw    = (unsigned short*)(ws + 58720256);   // 16 MiB
  unsigned short* yb     = (unsigned short*)(ws + 75497472);   // 16 MiB
  int*            rowl   = (int*)(ws + 92274688);              // 32 KiB
  int*            lcArr  = (int*)(ws + 92307456);              // 16 B

  prep<<<dim3(6148), 256, 0, stream>>>(x, wqkv, wproj, mask,
                                       xb, wqkvb, wprojb, rowl, lcArr);
  gemm_qkv<<<dim3(24, 64), 512, 0, stream>>>(xb, wqkvb, rowl, lcArr, qw, kw, vtw);
  attn_kernel<<<dim3(16, 64), 256, 0, stream>>>(qw, kw, vtw, lcArr, yb);
  gemm_proj<<<dim3(8, 64), 512, 0, stream>>>(yb, wprojb, (float*)d_out);
}